// Round 6
// baseline (162.348 us; speedup 1.0000x reference)
//
#include <hip/hip_runtime.h>
#include <math.h>

#define SQRT3F 1.7320508075688772f

typedef _Float16 half8 __attribute__((ext_vector_type(8)));
typedef _Float16 half4 __attribute__((ext_vector_type(4)));
typedef float    f32x4 __attribute__((ext_vector_type(4)));

// ---------------------------------------------------------------------------
// Fused Matern-3/2 Gram kernel.
//   Block: 512 threads (8 waves), output tile 128x128, K = D = 64 fully
//   LDS-resident -> ONE __syncthreads per block. 2 blocks/CU, 16 waves/CU.
//
//   fp32 accuracy via fp16 hi/lo split (hi=(f16)x, lo=(f16)(x-hi)):
//   dot ~= hi.hi + hi.lo + lo.hi  (3x v_mfma_f32_16x16x32_f16).
//
//   MFMA operand roles are SWAPPED (Z frag in the A slot): D[row][col] =
//   D[z-idx][x-idx], so lane&15 owns one output row m and regs walk 4
//   consecutive output cols n -> float4 (dwordx4) nontemporal stores,
//   16 rows x 64 contiguous bytes per store instruction (round-4 version
//   did 32 scalar dword stores/thread and plateaued ~2.6x above the
//   write roofline).
// ---------------------------------------------------------------------------
__global__ __launch_bounds__(512, 4)
void matern_mfma_kernel(const float* __restrict__ X,
                        const float* __restrict__ Z,
                        const float* __restrict__ sigma,
                        const float* __restrict__ lengthscale,
                        float* __restrict__ out,
                        int M) {
    __shared__ _Float16 Ah[128][72];
    __shared__ _Float16 Al[128][72];
    __shared__ _Float16 Bh[128][72];
    __shared__ _Float16 Bl[128][72];
    __shared__ float    x2s[128];
    __shared__ float    z2s[128];

    const int t  = threadIdx.x;
    const int n0 = blockIdx.x * 128;   // Z rows / output cols
    const int m0 = blockIdx.y * 128;   // X rows / output rows

    // ---------------- stage + convert + norms ----------------
    // flat float4 index f = t + 512*i ; row = f>>4 (0..127), c4 = f&15.
    // 16 consecutive threads share a row -> 16-lane shfl_xor reduce for norms.
    {
        float4 vx[4], vz[4];
        #pragma unroll
        for (int i = 0; i < 4; ++i) {
            const int f = t + 512 * i;
            vx[i] = *(const float4*)(X + (size_t)(m0 + (f >> 4)) * 64 + (f & 15) * 4);
        }
        #pragma unroll
        for (int i = 0; i < 4; ++i) {
            const int f = t + 512 * i;
            vz[i] = *(const float4*)(Z + (size_t)(n0 + (f >> 4)) * 64 + (f & 15) * 4);
        }
        #pragma unroll
        for (int i = 0; i < 4; ++i) {
            const int f   = t + 512 * i;
            const int row = f >> 4;
            const int c4  = f & 15;
            float4 v = vx[i];
            _Float16 hx = (_Float16)v.x, hy = (_Float16)v.y, hz = (_Float16)v.z, hw = (_Float16)v.w;
            half4 hv = { hx, hy, hz, hw };
            half4 lv = { (_Float16)(v.x - (float)hx), (_Float16)(v.y - (float)hy),
                         (_Float16)(v.z - (float)hz), (_Float16)(v.w - (float)hw) };
            *(half4*)&Ah[row][c4 * 4] = hv;
            *(half4*)&Al[row][c4 * 4] = lv;
            float ssq = v.x * v.x + v.y * v.y + v.z * v.z + v.w * v.w;
            ssq += __shfl_xor(ssq, 1, 16);
            ssq += __shfl_xor(ssq, 2, 16);
            ssq += __shfl_xor(ssq, 4, 16);
            ssq += __shfl_xor(ssq, 8, 16);
            if ((t & 15) == 0) x2s[row] = ssq;
        }
        #pragma unroll
        for (int i = 0; i < 4; ++i) {
            const int f   = t + 512 * i;
            const int row = f >> 4;
            const int c4  = f & 15;
            float4 v = vz[i];
            _Float16 hx = (_Float16)v.x, hy = (_Float16)v.y, hz = (_Float16)v.z, hw = (_Float16)v.w;
            half4 hv = { hx, hy, hz, hw };
            half4 lv = { (_Float16)(v.x - (float)hx), (_Float16)(v.y - (float)hy),
                         (_Float16)(v.z - (float)hz), (_Float16)(v.w - (float)hw) };
            *(half4*)&Bh[row][c4 * 4] = hv;
            *(half4*)&Bl[row][c4 * 4] = lv;
            float ssq = v.x * v.x + v.y * v.y + v.z * v.z + v.w * v.w;
            ssq += __shfl_xor(ssq, 1, 16);
            ssq += __shfl_xor(ssq, 2, 16);
            ssq += __shfl_xor(ssq, 4, 16);
            ssq += __shfl_xor(ssq, 8, 16);
            if ((t & 15) == 0) z2s[row] = ssq;
        }
    }
    __syncthreads();

    // ---------------- MFMA compute ----------------
    // 8 waves: 2 wave-rows x 4 wave-cols; each wave owns 64(m) x 32(n).
    const int lane = t & 63;
    const int w    = t >> 6;
    const int wr   = w >> 2;        // 0..1
    const int wc   = w & 3;         // 0..3
    const int lm   = lane & 15;
    const int q    = lane >> 4;

    f32x4 acc[4][2];
    #pragma unroll
    for (int a = 0; a < 4; ++a)
        #pragma unroll
        for (int b = 0; b < 2; ++b)
            acc[a][b] = (f32x4){0.f, 0.f, 0.f, 0.f};

    #pragma unroll
    for (int kc = 0; kc < 2; ++kc) {
        const int k = kc * 32 + q * 8;
        half8 ah[4], al[4], bh[2], bl[2];
        #pragma unroll
        for (int mt = 0; mt < 4; ++mt) {
            const int row = wr * 64 + mt * 16 + lm;
            ah[mt] = *(const half8*)&Ah[row][k];
            al[mt] = *(const half8*)&Al[row][k];
        }
        #pragma unroll
        for (int nt = 0; nt < 2; ++nt) {
            const int row = wc * 32 + nt * 16 + lm;
            bh[nt] = *(const half8*)&Bh[row][k];
            bl[nt] = *(const half8*)&Bl[row][k];
        }
        // Swapped operand roles: D[row=z-idx][col=x-idx].
        // Terms: hi_z.hi_x + hi_z.lo_x + lo_z.hi_x  ==  the 3 split terms.
        #pragma unroll
        for (int mt = 0; mt < 4; ++mt)
            #pragma unroll
            for (int nt = 0; nt < 2; ++nt) {
                acc[mt][nt] = __builtin_amdgcn_mfma_f32_16x16x32_f16(bh[nt], ah[mt], acc[mt][nt], 0, 0, 0);
                acc[mt][nt] = __builtin_amdgcn_mfma_f32_16x16x32_f16(bh[nt], al[mt], acc[mt][nt], 0, 0, 0);
                acc[mt][nt] = __builtin_amdgcn_mfma_f32_16x16x32_f16(bl[nt], ah[mt], acc[mt][nt], 0, 0, 0);
            }
    }

    // ---------------- epilogue ----------------
    // acc[mt][nt][r]: m = wr*64+mt*16+lm (lane-owned row),
    //                 n = wc*32+nt*16+q*4+r (regs walk 4 consecutive cols).
    const float s   = sigma[0];
    const float l   = lengthscale[0];
    const float fac = SQRT3F / l;
    const float s2  = s * s;

    #pragma unroll
    for (int mt = 0; mt < 4; ++mt) {
        const int m  = wr * 64 + mt * 16 + lm;
        const float xr = x2s[m];
        #pragma unroll
        for (int nt = 0; nt < 2; ++nt) {
            const int nc0 = wc * 32 + nt * 16 + q * 4;
            f32x4 zc = *(const f32x4*)&z2s[nc0];
            f32x4 res;
            #pragma unroll
            for (int r = 0; r < 4; ++r) {
                float sq  = xr + zc[r] - 2.0f * acc[mt][nt][r];
                float d   = __builtin_amdgcn_sqrtf(fmaxf(sq, 1e-12f));
                float val = fac * d;
                res[r] = s2 * (1.0f + val) * __expf(-val);
            }
            __builtin_nontemporal_store(res,
                (f32x4*)(out + (size_t)(m0 + m) * (size_t)M + n0 + nc0));
        }
    }
}

extern "C" void kernel_launch(void* const* d_in, const int* in_sizes, int n_in,
                              void* d_out, int out_size, void* d_ws, size_t ws_size,
                              hipStream_t stream) {
    (void)n_in; (void)out_size; (void)d_ws; (void)ws_size;
    const float* X   = (const float*)d_in[0];
    const float* Z   = (const float*)d_in[1];
    const float* sig = (const float*)d_in[2];
    const float* len = (const float*)d_in[3];
    float* out = (float*)d_out;

    const int D = 64;
    const int N = in_sizes[0] / D;   // 8192
    const int M = in_sizes[1] / D;   // 4096

    dim3 grid(M / 128, N / 128);
    matern_mfma_kernel<<<grid, 512, 0, stream>>>(X, Z, sig, len, out, M);
}